// Round 7
// baseline (16972.214 us; speedup 1.0000x reference)
//
#include <hip/hip_runtime.h>
#include <cstdint>

typedef float vf2 __attribute__((ext_vector_type(2)));

#define GB_M 128
#define GB_N 64
#define GB_K 16

// C[m,n] = act( sum_k A[row(m),k]*B[n,k] + bias[n] )
__global__ __launch_bounds__(256) void gemm_bt_f32(
    const float* __restrict__ A, const float* __restrict__ B,
    const float* __restrict__ bias, float* __restrict__ C,
    int Mc, int N, int K, int tc_shift, int Tfull, int t0, int act)
{
  __shared__ float As[GB_K][GB_M + 4];
  __shared__ float Bs[GB_K][GB_N + 4];
  const int tid = threadIdx.x;
  const int m0 = blockIdx.y * GB_M;
  const int n0 = blockIdx.x * GB_N;
  const int tx = tid & 15;
  const int ty = tid >> 4;

  const int tcmask = (1 << tc_shift) - 1;
  int arow[2];
#pragma unroll
  for (int i = 0; i < 2; i++) {
    int f = tid + i * 256;
    int row = f >> 2;
    int rc = m0 + row;
    arow[i] = (rc >> tc_shift) * Tfull + t0 + (rc & tcmask);
  }
  const int akq = tid & 3;
  const int brow = tid >> 2;
  const int bn = n0 + brow;

  vf2 acc2[4][4];
#pragma unroll
  for (int i = 0; i < 4; i++)
#pragma unroll
    for (int j = 0; j < 4; j++) acc2[i][j] = (vf2)(0.f);

  for (int k0 = 0; k0 < K; k0 += GB_K) {
#pragma unroll
    for (int i = 0; i < 2; i++) {
      int f = tid + i * 256;
      int row = f >> 2;
      float4 v = *(const float4*)(A + (size_t)arow[i] * K + k0 + akq * 4);
      As[akq * 4 + 0][row] = v.x; As[akq * 4 + 1][row] = v.y;
      As[akq * 4 + 2][row] = v.z; As[akq * 4 + 3][row] = v.w;
    }
    {
      float4 v = make_float4(0.f, 0.f, 0.f, 0.f);
      if (bn < N) v = *(const float4*)(B + (size_t)bn * K + k0 + akq * 4);
      Bs[akq * 4 + 0][brow] = v.x; Bs[akq * 4 + 1][brow] = v.y;
      Bs[akq * 4 + 2][brow] = v.z; Bs[akq * 4 + 3][brow] = v.w;
    }
    __syncthreads();
#pragma unroll
    for (int k = 0; k < GB_K; k++) {
      float4 a0 = *(const float4*)&As[k][ty * 8];
      float4 a1 = *(const float4*)&As[k][ty * 8 + 4];
      float4 b0 = *(const float4*)&Bs[k][tx * 4];
      vf2 a2[4];
      a2[0] = (vf2){a0.x, a0.y}; a2[1] = (vf2){a0.z, a0.w};
      a2[2] = (vf2){a1.x, a1.y}; a2[3] = (vf2){a1.z, a1.w};
      float bv[4] = {b0.x, b0.y, b0.z, b0.w};
#pragma unroll
      for (int j = 0; j < 4; j++) {
        vf2 bs = (vf2){bv[j], bv[j]};
#pragma unroll
        for (int ip = 0; ip < 4; ip++)
          acc2[ip][j] = __builtin_elementwise_fma(a2[ip], bs, acc2[ip][j]);
      }
    }
    __syncthreads();
  }

#pragma unroll
  for (int j = 0; j < 4; j++) {
    int n = n0 + tx * 4 + j;
    if (n >= N) continue;
    float bz = bias[n];
#pragma unroll
    for (int i = 0; i < 8; i++) {
      int m = m0 + ty * 8 + i;
      float x = ((i & 1) ? acc2[i >> 1][j].y : acc2[i >> 1][j].x) + bz;
      if (act == 1) {
        x = 1.0507009873554805f * (x > 0.f ? x : 1.6732632423543772f * (__expf(x) - 1.f));
      } else if (act == 2) {
        x = tanhf(x);
      }
      C[(size_t)m * N + n] = x;
    }
  }
}

#define RT 384

__device__ __forceinline__ void pollge(const unsigned* fp, unsigned want) {
  while (__hip_atomic_load(fp, __ATOMIC_RELAXED, __HIP_MEMORY_SCOPE_AGENT) < want)
    __builtin_amdgcn_s_sleep(1);
}

// r9 recurrence body (proven 12880us structure), parameterized by family
// pointers. Staggered X/Y, crossed flags free-riding the 2 barriers/step,
// single-poll staging (64 thr/batch, 12 floats), gi hoisted above polls.
__device__ __forceinline__ void rec_body(
    const float* __restrict__ gi, const float* __restrict__ w_hh,
    const float* __restrict__ b_hh, float* __restrict__ hb,
    unsigned* __restrict__ flags, float* __restrict__ seq,
    int t0, int Tc, int wg, float (*hs)[776])
{
  const int jg = wg & 63;
  const int sd = wg >> 6;
  const int j0 = jg * 12;
  const int tid = threadIdx.x;
  const int p  = tid >> 6;        // wave 0..5
  const int ks = tid & 63;        // lane

  unsigned* flagX_my = flags + (((0 * 4 + sd) * 64) + jg) * 16;
  unsigned* flagY_my = flags + (((1 * 4 + sd) * 64) + jg) * 16;

  float4 wreg[3][2][3];
#pragma unroll
  for (int g = 0; g < 3; g++)
#pragma unroll
    for (int j2 = 0; j2 < 2; j2++)
#pragma unroll
      for (int kk = 0; kk < 3; kk++)
        wreg[g][j2][kk] = *(const float4*)(
            w_hh + (size_t)(g * 768 + j0 + 2 * p + j2) * 768 + (kk * 64 + ks) * 4);

  const int j2l = (ks >> 2) & 1;
  const int cl  = ks & 3;
  const int j_out  = j0 + 2 * p + j2l;
  const int bX_out = 8 * sd + cl;
  const int bY_out = 8 * sd + 4 + cl;
  const float bhr = b_hh[j_out];
  const float bhz = b_hh[768 + j_out];
  const float bhn = b_hh[1536 + j_out];

  const int sbi = tid >> 6;           // 0..3 for tid<256
  const int sk  = tid & 63;           // == jg index
  const unsigned* fX_st = flags + (((0 * 4 + sd) * 64) + sk) * 16;
  const unsigned* fY_st = flags + (((1 * 4 + sd) * 64) + sk) * 16;

  const bool hi4 = (ks & 4) != 0;
  const bool hi2 = (ks & 2) != 0;
  const bool hi1 = (ks & 1) != 0;

  for (int tt = 0; tt < Tc; tt++) {
    const int t = t0 + tt;

    // ================= X half =================
    float gXr = 0.f, gXz = 0.f, gXn = 0.f;
    if (ks < 8) {
      const float* gX = gi + ((size_t)bX_out * Tc + tt) * 2304 + j_out;
      gXr = gX[0]; gXz = gX[768]; gXn = gX[1536];
    }
    if (tid < 256) {
      pollge(fX_st, (unsigned)t);
      const unsigned long long* src = (const unsigned long long*)
          (hb + (size_t)(t & 1) * 24576 + (size_t)(8 * sd + sbi) * 768) + sk * 6;
      unsigned long long v[6];
#pragma unroll
      for (int i = 0; i < 6; i++)
        v[i] = __hip_atomic_load(src + i, __ATOMIC_RELAXED, __HIP_MEMORY_SCOPE_AGENT);
      float* dst = &hs[sbi][sk * 12];
#pragma unroll
      for (int q = 0; q < 3; q++) {
        *(float4*)(dst + q * 4) = make_float4(
            __uint_as_float((unsigned)v[2 * q]),
            __uint_as_float((unsigned)(v[2 * q] >> 32)),
            __uint_as_float((unsigned)v[2 * q + 1]),
            __uint_as_float((unsigned)(v[2 * q + 1] >> 32)));
      }
    }
    __syncthreads();   // BAR1: hs X ready; drains outY(t) stores of prev round
    if (tid == 0)
      __hip_atomic_store(flagY_my, (unsigned)t, __ATOMIC_RELAXED, __HIP_MEMORY_SCOPE_AGENT);

    float r3[3];
    {
      vf2 a2[3][2][4];
#pragma unroll
      for (int g = 0; g < 3; g++)
#pragma unroll
        for (int j2 = 0; j2 < 2; j2++)
#pragma unroll
          for (int c = 0; c < 4; c++) a2[g][j2][c] = (vf2)(0.f);
#pragma unroll
      for (int kk = 0; kk < 3; kk++) {
        const int off = (kk * 64 + ks) * 4;
        vf2 hlo[4], hhi[4];
#pragma unroll
        for (int c = 0; c < 4; c++) {
          float4 h = *(const float4*)(&hs[c][0] + off);
          hlo[c] = (vf2){h.x, h.y};
          hhi[c] = (vf2){h.z, h.w};
        }
#pragma unroll
        for (int g = 0; g < 3; g++)
#pragma unroll
          for (int j2 = 0; j2 < 2; j2++) {
            float4 w = wreg[g][j2][kk];
            vf2 wlo = (vf2){w.x, w.y};
            vf2 whi = (vf2){w.z, w.w};
#pragma unroll
            for (int c = 0; c < 4; c++) {
              a2[g][j2][c] = __builtin_elementwise_fma(wlo, hlo[c], a2[g][j2][c]);
              a2[g][j2][c] = __builtin_elementwise_fma(whi, hhi[c], a2[g][j2][c]);
            }
          }
      }
      float acc[3][2][4];
#pragma unroll
      for (int g = 0; g < 3; g++)
#pragma unroll
        for (int j2 = 0; j2 < 2; j2++)
#pragma unroll
          for (int c = 0; c < 4; c++) acc[g][j2][c] = a2[g][j2][c].x + a2[g][j2][c].y;

      float r12[3][4];
#pragma unroll
      for (int g = 0; g < 3; g++)
#pragma unroll
        for (int c = 0; c < 4; c++) {
          float send = hi4 ? acc[g][0][c] : acc[g][1][c];
          float keep = hi4 ? acc[g][1][c] : acc[g][0][c];
          r12[g][c] = keep + __shfl_xor(send, 4);
        }
      float r6[3][2];
#pragma unroll
      for (int g = 0; g < 3; g++)
#pragma unroll
        for (int c2 = 0; c2 < 2; c2++) {
          float send = hi2 ? r12[g][c2] : r12[g][2 + c2];
          float keep = hi2 ? r12[g][2 + c2] : r12[g][c2];
          r6[g][c2] = keep + __shfl_xor(send, 2);
        }
#pragma unroll
      for (int g = 0; g < 3; g++) {
        float send = hi1 ? r6[g][0] : r6[g][1];
        float keep = hi1 ? r6[g][1] : r6[g][0];
        r3[g] = keep + __shfl_xor(send, 1);
      }
#pragma unroll
      for (int g = 0; g < 3; g++) {
        r3[g] += __shfl_xor(r3[g], 8);
        r3[g] += __shfl_xor(r3[g], 16);
        r3[g] += __shfl_xor(r3[g], 32);
      }
    }
    if (ks < 8) {
      float hp = hs[cl][j_out];
      float r = 1.f / (1.f + __expf(-(gXr + r3[0] + bhr)));
      float z = 1.f / (1.f + __expf(-(gXz + r3[1] + bhz)));
      float n = tanhf(gXn + r * (r3[2] + bhn));
      float hv = (1.f - z) * n + z * hp;
      __hip_atomic_store(hb + (size_t)((t + 1) & 1) * 24576 + (size_t)bX_out * 768 + j_out,
                         hv, __ATOMIC_RELAXED, __HIP_MEMORY_SCOPE_AGENT);
      seq[((size_t)bX_out * 1024 + t) * 768 + j_out] = hv;
    }

    // ================= Y half =================
    float gYr = 0.f, gYz = 0.f, gYn = 0.f;
    if (ks < 8) {
      const float* gY = gi + ((size_t)bY_out * Tc + tt) * 2304 + j_out;
      gYr = gY[0]; gYz = gY[768]; gYn = gY[1536];
    }
    if (tid < 256) {
      pollge(fY_st, (unsigned)t);
      const unsigned long long* src = (const unsigned long long*)
          (hb + (size_t)(t & 1) * 24576 + (size_t)(8 * sd + 4 + sbi) * 768) + sk * 6;
      unsigned long long v[6];
#pragma unroll
      for (int i = 0; i < 6; i++)
        v[i] = __hip_atomic_load(src + i, __ATOMIC_RELAXED, __HIP_MEMORY_SCOPE_AGENT);
      float* dst = &hs[4 + sbi][sk * 12];
#pragma unroll
      for (int q = 0; q < 3; q++) {
        *(float4*)(dst + q * 4) = make_float4(
            __uint_as_float((unsigned)v[2 * q]),
            __uint_as_float((unsigned)(v[2 * q] >> 32)),
            __uint_as_float((unsigned)v[2 * q + 1]),
            __uint_as_float((unsigned)(v[2 * q + 1] >> 32)));
      }
    }
    __syncthreads();   // BAR2: hs Y ready; drains outX(t+1) stores
    if (tid == 0)
      __hip_atomic_store(flagX_my, (unsigned)(t + 1), __ATOMIC_RELAXED, __HIP_MEMORY_SCOPE_AGENT);

    {
      vf2 a2[3][2][4];
#pragma unroll
      for (int g = 0; g < 3; g++)
#pragma unroll
        for (int j2 = 0; j2 < 2; j2++)
#pragma unroll
          for (int c = 0; c < 4; c++) a2[g][j2][c] = (vf2)(0.f);
#pragma unroll
      for (int kk = 0; kk < 3; kk++) {
        const int off = (kk * 64 + ks) * 4;
        vf2 hlo[4], hhi[4];
#pragma unroll
        for (int c = 0; c < 4; c++) {
          float4 h = *(const float4*)(&hs[4 + c][0] + off);
          hlo[c] = (vf2){h.x, h.y};
          hhi[c] = (vf2){h.z, h.w};
        }
#pragma unroll
        for (int g = 0; g < 3; g++)
#pragma unroll
          for (int j2 = 0; j2 < 2; j2++) {
            float4 w = wreg[g][j2][kk];
            vf2 wlo = (vf2){w.x, w.y};
            vf2 whi = (vf2){w.z, w.w};
#pragma unroll
            for (int c = 0; c < 4; c++) {
              a2[g][j2][c] = __builtin_elementwise_fma(wlo, hlo[c], a2[g][j2][c]);
              a2[g][j2][c] = __builtin_elementwise_fma(whi, hhi[c], a2[g][j2][c]);
            }
          }
      }
      float acc[3][2][4];
#pragma unroll
      for (int g = 0; g < 3; g++)
#pragma unroll
        for (int j2 = 0; j2 < 2; j2++)
#pragma unroll
          for (int c = 0; c < 4; c++) acc[g][j2][c] = a2[g][j2][c].x + a2[g][j2][c].y;

      float r12[3][4];
#pragma unroll
      for (int g = 0; g < 3; g++)
#pragma unroll
        for (int c = 0; c < 4; c++) {
          float send = hi4 ? acc[g][0][c] : acc[g][1][c];
          float keep = hi4 ? acc[g][1][c] : acc[g][0][c];
          r12[g][c] = keep + __shfl_xor(send, 4);
        }
      float r6[3][2];
#pragma unroll
      for (int g = 0; g < 3; g++)
#pragma unroll
        for (int c2 = 0; c2 < 2; c2++) {
          float send = hi2 ? r12[g][c2] : r12[g][2 + c2];
          float keep = hi2 ? r12[g][2 + c2] : r12[g][c2];
          r6[g][c2] = keep + __shfl_xor(send, 2);
        }
#pragma unroll
      for (int g = 0; g < 3; g++) {
        float send = hi1 ? r6[g][0] : r6[g][1];
        float keep = hi1 ? r6[g][1] : r6[g][0];
        r3[g] = keep + __shfl_xor(send, 1);
      }
#pragma unroll
      for (int g = 0; g < 3; g++) {
        r3[g] += __shfl_xor(r3[g], 8);
        r3[g] += __shfl_xor(r3[g], 16);
        r3[g] += __shfl_xor(r3[g], 32);
      }
    }
    if (ks < 8) {
      float hp = hs[4 + cl][j_out];
      float r = 1.f / (1.f + __expf(-(gYr + r3[0] + bhr)));
      float z = 1.f / (1.f + __expf(-(gYz + r3[1] + bhz)));
      float n = tanhf(gYn + r * (r3[2] + bhn));
      float hv = (1.f - z) * n + z * hp;
      __hip_atomic_store(hb + (size_t)((t + 1) & 1) * 24576 + (size_t)bY_out * 768 + j_out,
                         hv, __ATOMIC_RELAXED, __HIP_MEMORY_SCOPE_AGENT);
      seq[((size_t)bY_out * 1024 + t) * 768 + j_out] = hv;
    }
  }
  // tail: publish Y's final step so the next dispatch can start
  __syncthreads();
  if (tid == 0)
    __hip_atomic_store(flagY_my, (unsigned)(t0 + Tc), __ATOMIC_RELAXED, __HIP_MEMORY_SCOPE_AGENT);
}

// Two co-resident families: A (WGs 0-255) = layer-0 chunk c; B (WGs 256-511)
// = layer-1 chunk c-1. Independent flags/hb/seq per family -> no cross-family
// waits. __launch_bounds__(384,3) caps VGPR at 170 (actual ~100) so 2 WGs/CU
// are guaranteed -> all 512 WGs co-resident (required for lag-1 safety).
__global__ __launch_bounds__(RT, 3) void gru_rec2(
    const float* __restrict__ gi0, const float* __restrict__ w_hh0,
    const float* __restrict__ b_hh0, float* __restrict__ hb0,
    unsigned* __restrict__ flags0, float* __restrict__ seq0,
    const float* __restrict__ gi1, const float* __restrict__ w_hh1,
    const float* __restrict__ b_hh1, float* __restrict__ hb1,
    unsigned* __restrict__ flags1, float* __restrict__ seq1,
    int t0a, int Tc, int enA, int enB)
{
  __shared__ float hs[8][776];
  const int bid = blockIdx.x;
  const int fam = bid >> 8;
  const int wg = bid & 255;
  if (fam == 0) {
    if (!enA) return;
    rec_body(gi0, w_hh0, b_hh0, hb0, flags0, seq0, t0a, Tc, wg, hs);
  } else {
    if (!enB) return;
    rec_body(gi1, w_hh1, b_hh1, hb1, flags1, seq1, t0a - 256, Tc, wg, hs);
  }
}

extern "C" void kernel_launch(void* const* d_in, const int* in_sizes, int n_in,
                              void* d_out, int out_size, void* d_ws, size_t ws_size,
                              hipStream_t stream) {
  const float* feat  = (const float*)d_in[0];
  const float* w_ih0 = (const float*)d_in[2];
  const float* w_hh0 = (const float*)d_in[3];
  const float* b_ih0 = (const float*)d_in[4];
  const float* b_hh0 = (const float*)d_in[5];
  const float* w_ih1 = (const float*)d_in[6];
  const float* w_hh1 = (const float*)d_in[7];
  const float* b_ih1 = (const float*)d_in[8];
  const float* b_hh1 = (const float*)d_in[9];
  const float* fc_w  = (const float*)d_in[10];
  const float* fc_b  = (const float*)d_in[11];
  const float* out_w = (const float*)d_in[12];
  const float* out_b = (const float*)d_in[13];
  float* out = (float*)d_out;

  const int Tc = 256;
  const size_t PROJ = (size_t)32 * Tc * 2304;    // 18,874,368 f per layer-chunk
  const size_t SEQ  = (size_t)32 * 1024 * 768;   // 25,165,824 f

  float* proj0 = (float*)d_ws;
  float* proj1 = proj0 + PROJ;
  float* seq0  = proj1 + PROJ;
  float* seq1  = seq0 + SEQ;
  float* hb0   = seq1 + SEQ;                     // 2 x 24576 f
  float* hb1   = hb0 + 2 * 24576;
  unsigned* flags0 = (unsigned*)(hb1 + 2 * 24576);   // 8192 u32
  unsigned* flags1 = flags0 + 8192;

  hipMemsetAsync(hb0, 0, 4 * 24576 * sizeof(float), stream);   // hb0 + hb1
  hipMemsetAsync(flags0, 0, 65536, stream);                    // flags0 + flags1

  auto G0 = [&](int c) {
    gemm_bt_f32<<<dim3(36, 64), dim3(256), 0, stream>>>(
        feat, w_ih0, b_ih0, proj0, 8192, 2304, 768, 8, 1024, c * Tc, 0);
  };
  auto G1 = [&](int c) {
    gemm_bt_f32<<<dim3(36, 64), dim3(256), 0, stream>>>(
        seq0, w_ih1, b_ih1, proj1, 8192, 2304, 768, 8, 1024, c * Tc, 0);
  };
  auto R = [&](int t0a, int eA, int eB) {
    gru_rec2<<<dim3(512), dim3(RT), 0, stream>>>(
        proj0, w_hh0, b_hh0, hb0, flags0, seq0,
        proj1, w_hh1, b_hh1, hb1, flags1, seq1, t0a, Tc, eA, eB);
  };

  G0(0);        R(0, 1, 0);
  G0(1); G1(0); R(256, 1, 1);
  G0(2); G1(1); R(512, 1, 1);
  G0(3); G1(2); R(768, 1, 1);
  G1(3);        R(1024, 0, 1);

  // ---- fc + SELU ----
  gemm_bt_f32<<<dim3(8, 256), dim3(256), 0, stream>>>(
      seq1, fc_w, fc_b, proj0, 32768, 512, 768, 15, 32768, 0, 1);
  // ---- out + tanh ----
  gemm_bt_f32<<<dim3(1, 256), dim3(256), 0, stream>>>(
      proj0, out_w, out_b, out, 32768, 39, 512, 15, 32768, 0, 2);
}

// Round 8
// 12292.158 us; speedup vs baseline: 1.3807x; 1.3807x over previous
//
#include <hip/hip_runtime.h>
#include <cstdint>

typedef float vf2 __attribute__((ext_vector_type(2)));

#define GB_M 128
#define GB_N 64
#define GB_K 16

// C[m,n] = act( sum_k A[row(m),k]*B[n,k] + bias[n] )
__global__ __launch_bounds__(256) void gemm_bt_f32(
    const float* __restrict__ A, const float* __restrict__ B,
    const float* __restrict__ bias, float* __restrict__ C,
    int Mc, int N, int K, int tc_shift, int Tfull, int t0, int act)
{
  __shared__ float As[GB_K][GB_M + 4];
  __shared__ float Bs[GB_K][GB_N + 4];
  const int tid = threadIdx.x;
  const int m0 = blockIdx.y * GB_M;
  const int n0 = blockIdx.x * GB_N;
  const int tx = tid & 15;
  const int ty = tid >> 4;

  const int tcmask = (1 << tc_shift) - 1;
  int arow[2];
#pragma unroll
  for (int i = 0; i < 2; i++) {
    int f = tid + i * 256;
    int row = f >> 2;
    int rc = m0 + row;
    arow[i] = (rc >> tc_shift) * Tfull + t0 + (rc & tcmask);
  }
  const int akq = tid & 3;
  const int brow = tid >> 2;
  const int bn = n0 + brow;

  vf2 acc2[4][4];
#pragma unroll
  for (int i = 0; i < 4; i++)
#pragma unroll
    for (int j = 0; j < 4; j++) acc2[i][j] = (vf2)(0.f);

  for (int k0 = 0; k0 < K; k0 += GB_K) {
#pragma unroll
    for (int i = 0; i < 2; i++) {
      int f = tid + i * 256;
      int row = f >> 2;
      float4 v = *(const float4*)(A + (size_t)arow[i] * K + k0 + akq * 4);
      As[akq * 4 + 0][row] = v.x; As[akq * 4 + 1][row] = v.y;
      As[akq * 4 + 2][row] = v.z; As[akq * 4 + 3][row] = v.w;
    }
    {
      float4 v = make_float4(0.f, 0.f, 0.f, 0.f);
      if (bn < N) v = *(const float4*)(B + (size_t)bn * K + k0 + akq * 4);
      Bs[akq * 4 + 0][brow] = v.x; Bs[akq * 4 + 1][brow] = v.y;
      Bs[akq * 4 + 2][brow] = v.z; Bs[akq * 4 + 3][brow] = v.w;
    }
    __syncthreads();
#pragma unroll
    for (int k = 0; k < GB_K; k++) {
      float4 a0 = *(const float4*)&As[k][ty * 8];
      float4 a1 = *(const float4*)&As[k][ty * 8 + 4];
      float4 b0 = *(const float4*)&Bs[k][tx * 4];
      vf2 a2[4];
      a2[0] = (vf2){a0.x, a0.y}; a2[1] = (vf2){a0.z, a0.w};
      a2[2] = (vf2){a1.x, a1.y}; a2[3] = (vf2){a1.z, a1.w};
      float bv[4] = {b0.x, b0.y, b0.z, b0.w};
#pragma unroll
      for (int j = 0; j < 4; j++) {
        vf2 bs = (vf2){bv[j], bv[j]};
#pragma unroll
        for (int ip = 0; ip < 4; ip++)
          acc2[ip][j] = __builtin_elementwise_fma(a2[ip], bs, acc2[ip][j]);
      }
    }
    __syncthreads();
  }

#pragma unroll
  for (int j = 0; j < 4; j++) {
    int n = n0 + tx * 4 + j;
    if (n >= N) continue;
    float bz = bias[n];
#pragma unroll
    for (int i = 0; i < 8; i++) {
      int m = m0 + ty * 8 + i;
      float x = ((i & 1) ? acc2[i >> 1][j].y : acc2[i >> 1][j].x) + bz;
      if (act == 1) {
        x = 1.0507009873554805f * (x > 0.f ? x : 1.6732632423543772f * (__expf(x) - 1.f));
      } else if (act == 2) {
        x = tanhf(x);
      }
      C[(size_t)m * N + n] = x;
    }
  }
}

#define RT 384
#define RNWG 256

// Persistent GRU recurrence, round-11: r9 staggered X/Y structure (proven
// 12880us winner) with the flag protocol replaced by SELF-PUBLISHING u64
// granules {tag:u32 | h:f32bits}, stored with one agent-scope atomic right
// after the gate computation. No flags, no publish-after-barrier: the store
// IS the publish, and the consumer's poll-hit delivers the data inline
// (2 serial RTs -> 1). Coalescing fixed vs round-3: staging thread sk loads
// granules {sk + 64*i} (lane-adjacent, 512B/instr). Lag-1 overwrite safety:
// P stores X(t+1) => P staged X(t) => every producer stored X(t) => every
// consumer staged X(t-1) (whose parity slot X(t+1) overwrites). Barriers
// remain only for the intra-WG hs LDS lifecycle (2/step, as r9).
__global__ __launch_bounds__(RT, 1) void gru_rec(
    const float* __restrict__ gi, const float* __restrict__ w_hh,
    const float* __restrict__ b_hh, unsigned long long* __restrict__ gx,
    float* __restrict__ seq, int t0, int Tc)
{
  __shared__ float hs[8][776];    // rows 0-3: X batches, 4-7: Y batches
  const int wg = blockIdx.x;
  const int jg = wg & 63;
  const int sd = wg >> 6;
  const int j0 = jg * 12;
  const int tid = threadIdx.x;
  const int p  = tid >> 6;        // wave 0..5
  const int ks = tid & 63;        // lane

  // ---- W slice into registers: [g][j2][kk], row g*768+j0+2p+j2, 16B at (kk*64+ks)*4
  float4 wreg[3][2][3];
#pragma unroll
  for (int g = 0; g < 3; g++)
#pragma unroll
    for (int j2 = 0; j2 < 2; j2++)
#pragma unroll
      for (int kk = 0; kk < 3; kk++)
        wreg[g][j2][kk] = *(const float4*)(
            w_hh + (size_t)(g * 768 + j0 + 2 * p + j2) * 768 + (kk * 64 + ks) * 4);

  const int j2l = (ks >> 2) & 1;
  const int cl  = ks & 3;
  const int j_out  = j0 + 2 * p + j2l;
  const int bX_out = 8 * sd + cl;
  const int bY_out = 8 * sd + 4 + cl;
  const float bhr = b_hh[j_out];
  const float bhz = b_hh[768 + j_out];
  const float bhn = b_hh[1536 + j_out];

  // staging: tid<256; 64 threads per batch (sbi=tid>>6), thread sk covers
  // dims {sk + 64*i, i=0..11} -> coalesced granule loads, conflict-free LDS
  const int sbi = tid >> 6;           // 0..3 (batch within half)
  const int sk  = tid & 63;

  const bool hi4 = (ks & 4) != 0;
  const bool hi2 = (ks & 2) != 0;
  const bool hi1 = (ks & 1) != 0;

  for (int tt = 0; tt < Tc; tt++) {
    const int t = t0 + tt;
    const unsigned wantt = (unsigned)t;

    // ================= X half =================
    float gXr = 0.f, gXz = 0.f, gXn = 0.f;
    if (ks < 8) {
      const float* gX = gi + ((size_t)bX_out * Tc + tt) * 2304 + j_out;
      gXr = gX[0]; gXz = gX[768]; gXn = gX[1536];
    }
    if (tid < 256) {
      const unsigned long long* src =
          gx + (size_t)(t & 1) * 24576 + (size_t)(8 * sd + sbi) * 768 + sk;
      unsigned long long v[12];
#pragma unroll
      for (int i = 0; i < 12; i++)
        v[i] = __hip_atomic_load(src + 64 * i, __ATOMIC_RELAXED, __HIP_MEMORY_SCOPE_AGENT);
      while (true) {
        unsigned miss = 0;
#pragma unroll
        for (int i = 0; i < 12; i++)
          miss |= (unsigned)((unsigned)(v[i] >> 32) < wantt);
        if (!miss) break;
        __builtin_amdgcn_s_sleep(1);
#pragma unroll
        for (int i = 0; i < 12; i++)
          if ((unsigned)(v[i] >> 32) < wantt)
            v[i] = __hip_atomic_load(src + 64 * i, __ATOMIC_RELAXED, __HIP_MEMORY_SCOPE_AGENT);
      }
#pragma unroll
      for (int i = 0; i < 12; i++)
        hs[sbi][sk + 64 * i] = __uint_as_float((unsigned)v[i]);
    }
    __syncthreads();   // BAR1: hs X ready

    float r3[3];
    {
      vf2 a2[3][2][4];
#pragma unroll
      for (int g = 0; g < 3; g++)
#pragma unroll
        for (int j2 = 0; j2 < 2; j2++)
#pragma unroll
          for (int c = 0; c < 4; c++) a2[g][j2][c] = (vf2)(0.f);
#pragma unroll
      for (int kk = 0; kk < 3; kk++) {
        const int off = (kk * 64 + ks) * 4;
        vf2 hlo[4], hhi[4];
#pragma unroll
        for (int c = 0; c < 4; c++) {
          float4 h = *(const float4*)(&hs[c][0] + off);
          hlo[c] = (vf2){h.x, h.y};
          hhi[c] = (vf2){h.z, h.w};
        }
#pragma unroll
        for (int g = 0; g < 3; g++)
#pragma unroll
          for (int j2 = 0; j2 < 2; j2++) {
            float4 w = wreg[g][j2][kk];
            vf2 wlo = (vf2){w.x, w.y};
            vf2 whi = (vf2){w.z, w.w};
#pragma unroll
            for (int c = 0; c < 4; c++) {
              a2[g][j2][c] = __builtin_elementwise_fma(wlo, hlo[c], a2[g][j2][c]);
              a2[g][j2][c] = __builtin_elementwise_fma(whi, hhi[c], a2[g][j2][c]);
            }
          }
      }
      float acc[3][2][4];
#pragma unroll
      for (int g = 0; g < 3; g++)
#pragma unroll
        for (int j2 = 0; j2 < 2; j2++)
#pragma unroll
          for (int c = 0; c < 4; c++) acc[g][j2][c] = a2[g][j2][c].x + a2[g][j2][c].y;

      float r12[3][4];
#pragma unroll
      for (int g = 0; g < 3; g++)
#pragma unroll
        for (int c = 0; c < 4; c++) {
          float send = hi4 ? acc[g][0][c] : acc[g][1][c];
          float keep = hi4 ? acc[g][1][c] : acc[g][0][c];
          r12[g][c] = keep + __shfl_xor(send, 4);
        }
      float r6[3][2];
#pragma unroll
      for (int g = 0; g < 3; g++)
#pragma unroll
        for (int c2 = 0; c2 < 2; c2++) {
          float send = hi2 ? r12[g][c2] : r12[g][2 + c2];
          float keep = hi2 ? r12[g][2 + c2] : r12[g][c2];
          r6[g][c2] = keep + __shfl_xor(send, 2);
        }
#pragma unroll
      for (int g = 0; g < 3; g++) {
        float send = hi1 ? r6[g][0] : r6[g][1];
        float keep = hi1 ? r6[g][1] : r6[g][0];
        r3[g] = keep + __shfl_xor(send, 1);
      }
#pragma unroll
      for (int g = 0; g < 3; g++) {
        r3[g] += __shfl_xor(r3[g], 8);
        r3[g] += __shfl_xor(r3[g], 16);
        r3[g] += __shfl_xor(r3[g], 32);
      }
    }
    if (ks < 8) {
      float hp = hs[cl][j_out];
      float r = 1.f / (1.f + __expf(-(gXr + r3[0] + bhr)));
      float z = 1.f / (1.f + __expf(-(gXz + r3[1] + bhz)));
      float n = tanhf(gXn + r * (r3[2] + bhn));
      float hv = (1.f - z) * n + z * hp;
      // granule store IS the publish (tag t+1 travels with the data)
      __hip_atomic_store(
          gx + (size_t)((t + 1) & 1) * 24576 + (size_t)bX_out * 768 + j_out,
          ((unsigned long long)(unsigned)(t + 1) << 32) |
              (unsigned long long)__float_as_uint(hv),
          __ATOMIC_RELAXED, __HIP_MEMORY_SCOPE_AGENT);
      seq[((size_t)bX_out * 1024 + t) * 768 + j_out] = hv;
    }

    // ================= Y half =================
    float gYr = 0.f, gYz = 0.f, gYn = 0.f;
    if (ks < 8) {
      const float* gY = gi + ((size_t)bY_out * Tc + tt) * 2304 + j_out;
      gYr = gY[0]; gYz = gY[768]; gYn = gY[1536];
    }
    if (tid < 256) {
      const unsigned long long* src =
          gx + (size_t)(t & 1) * 24576 + (size_t)(8 * sd + 4 + sbi) * 768 + sk;
      unsigned long long v[12];
#pragma unroll
      for (int i = 0; i < 12; i++)
        v[i] = __hip_atomic_load(src + 64 * i, __ATOMIC_RELAXED, __HIP_MEMORY_SCOPE_AGENT);
      while (true) {
        unsigned miss = 0;
#pragma unroll
        for (int i = 0; i < 12; i++)
          miss |= (unsigned)((unsigned)(v[i] >> 32) < wantt);
        if (!miss) break;
        __builtin_amdgcn_s_sleep(1);
#pragma unroll
        for (int i = 0; i < 12; i++)
          if ((unsigned)(v[i] >> 32) < wantt)
            v[i] = __hip_atomic_load(src + 64 * i, __ATOMIC_RELAXED, __HIP_MEMORY_SCOPE_AGENT);
      }
#pragma unroll
      for (int i = 0; i < 12; i++)
        hs[4 + sbi][sk + 64 * i] = __uint_as_float((unsigned)v[i]);
    }
    __syncthreads();   // BAR2: hs Y ready

    {
      vf2 a2[3][2][4];
#pragma unroll
      for (int g = 0; g < 3; g++)
#pragma unroll
        for (int j2 = 0; j2 < 2; j2++)
#pragma unroll
          for (int c = 0; c < 4; c++) a2[g][j2][c] = (vf2)(0.f);
#pragma unroll
      for (int kk = 0; kk < 3; kk++) {
        const int off = (kk * 64 + ks) * 4;
        vf2 hlo[4], hhi[4];
#pragma unroll
        for (int c = 0; c < 4; c++) {
          float4 h = *(const float4*)(&hs[4 + c][0] + off);
          hlo[c] = (vf2){h.x, h.y};
          hhi[c] = (vf2){h.z, h.w};
        }
#pragma unroll
        for (int g = 0; g < 3; g++)
#pragma unroll
          for (int j2 = 0; j2 < 2; j2++) {
            float4 w = wreg[g][j2][kk];
            vf2 wlo = (vf2){w.x, w.y};
            vf2 whi = (vf2){w.z, w.w};
#pragma unroll
            for (int c = 0; c < 4; c++) {
              a2[g][j2][c] = __builtin_elementwise_fma(wlo, hlo[c], a2[g][j2][c]);
              a2[g][j2][c] = __builtin_elementwise_fma(whi, hhi[c], a2[g][j2][c]);
            }
          }
      }
      float acc[3][2][4];
#pragma unroll
      for (int g = 0; g < 3; g++)
#pragma unroll
        for (int j2 = 0; j2 < 2; j2++)
#pragma unroll
          for (int c = 0; c < 4; c++) acc[g][j2][c] = a2[g][j2][c].x + a2[g][j2][c].y;

      float r12[3][4];
#pragma unroll
      for (int g = 0; g < 3; g++)
#pragma unroll
        for (int c = 0; c < 4; c++) {
          float send = hi4 ? acc[g][0][c] : acc[g][1][c];
          float keep = hi4 ? acc[g][1][c] : acc[g][0][c];
          r12[g][c] = keep + __shfl_xor(send, 4);
        }
      float r6[3][2];
#pragma unroll
      for (int g = 0; g < 3; g++)
#pragma unroll
        for (int c2 = 0; c2 < 2; c2++) {
          float send = hi2 ? r12[g][c2] : r12[g][2 + c2];
          float keep = hi2 ? r12[g][2 + c2] : r12[g][c2];
          r6[g][c2] = keep + __shfl_xor(send, 2);
        }
#pragma unroll
      for (int g = 0; g < 3; g++) {
        float send = hi1 ? r6[g][0] : r6[g][1];
        float keep = hi1 ? r6[g][1] : r6[g][0];
        r3[g] = keep + __shfl_xor(send, 1);
      }
#pragma unroll
      for (int g = 0; g < 3; g++) {
        r3[g] += __shfl_xor(r3[g], 8);
        r3[g] += __shfl_xor(r3[g], 16);
        r3[g] += __shfl_xor(r3[g], 32);
      }
    }
    if (ks < 8) {
      float hp = hs[4 + cl][j_out];
      float r = 1.f / (1.f + __expf(-(gYr + r3[0] + bhr)));
      float z = 1.f / (1.f + __expf(-(gYz + r3[1] + bhz)));
      float n = tanhf(gYn + r * (r3[2] + bhn));
      float hv = (1.f - z) * n + z * hp;
      __hip_atomic_store(
          gx + (size_t)((t + 1) & 1) * 24576 + (size_t)bY_out * 768 + j_out,
          ((unsigned long long)(unsigned)(t + 1) << 32) |
              (unsigned long long)__float_as_uint(hv),
          __ATOMIC_RELAXED, __HIP_MEMORY_SCOPE_AGENT);
      seq[((size_t)bY_out * 1024 + t) * 768 + j_out] = hv;
    }
  }
}

extern "C" void kernel_launch(void* const* d_in, const int* in_sizes, int n_in,
                              void* d_out, int out_size, void* d_ws, size_t ws_size,
                              hipStream_t stream) {
  const float* feat  = (const float*)d_in[0];
  const float* w_ih0 = (const float*)d_in[2];
  const float* w_hh0 = (const float*)d_in[3];
  const float* b_ih0 = (const float*)d_in[4];
  const float* b_hh0 = (const float*)d_in[5];
  const float* w_ih1 = (const float*)d_in[6];
  const float* w_hh1 = (const float*)d_in[7];
  const float* b_ih1 = (const float*)d_in[8];
  const float* b_hh1 = (const float*)d_in[9];
  const float* fc_w  = (const float*)d_in[10];
  const float* fc_b  = (const float*)d_in[11];
  const float* out_w = (const float*)d_in[12];
  const float* out_b = (const float*)d_in[13];
  float* out = (float*)d_out;

  const int Tc = 256;
  const int McChunk = 32 * Tc;

  float* proj = (float*)d_ws;                               // 18,874,368 f
  float* seq  = proj + (size_t)32 * Tc * 2304;              // 25,165,824 f
  unsigned long long* gx = (unsigned long long*)(seq + (size_t)25165824);
  const size_t GXB = (size_t)2 * 24576 * 8;                 // 393,216 B

  // ---- layer 0 ----
  hipMemsetAsync(gx, 0, GXB, stream);   // tags=0, h=0 -> h(0)=0, poll t=0 passes
  for (int c = 0; c < 4; c++) {
    gemm_bt_f32<<<dim3(36, McChunk / 128), dim3(256), 0, stream>>>(
        feat, w_ih0, b_ih0, proj, McChunk, 2304, 768, 8, 1024, c * Tc, 0);
    gru_rec<<<dim3(RNWG), dim3(RT), 0, stream>>>(
        proj, w_hh0, b_hh0, gx, seq, c * Tc, Tc);
  }
  // ---- layer 1 ----
  hipMemsetAsync(gx, 0, GXB, stream);
  for (int c = 0; c < 4; c++) {
    gemm_bt_f32<<<dim3(36, McChunk / 128), dim3(256), 0, stream>>>(
        seq, w_ih1, b_ih1, proj, McChunk, 2304, 768, 8, 1024, c * Tc, 0);
    gru_rec<<<dim3(RNWG), dim3(RT), 0, stream>>>(
        proj, w_hh1, b_hh1, gx, seq, c * Tc, Tc);
  }
  // ---- fc + SELU ----
  gemm_bt_f32<<<dim3(8, 256), dim3(256), 0, stream>>>(
      seq, fc_w, fc_b, proj, 32768, 512, 768, 15, 32768, 0, 1);
  // ---- out + tanh ----
  gemm_bt_f32<<<dim3(1, 256), dim3(256), 0, stream>>>(
      proj, out_w, out_b, out, 32768, 39, 512, 15, 32768, 0, 2);
}